// Round 6
// baseline (2446.394 us; speedup 1.0000x reference)
//
#include <hip/hip_runtime.h>
#include <hip/hip_bf16.h>
#include <cstdint>
#include <cstddef>

#define EMB 128
#define NLIG 32768
#define NREC 262144
#define NGRAPH 1024
#define ELIG 327680
#define EREC 2097152
#define BN_EPS 1e-5f

typedef unsigned short ushort_t;
typedef short bf16x8 __attribute__((ext_vector_type(8)));
typedef float f32x4 __attribute__((ext_vector_type(4)));

__device__ __forceinline__ float bf2f(ushort_t u) {
  union { unsigned int i; float f; } v;
  v.i = ((unsigned int)u) << 16;
  return v.f;
}
__device__ __forceinline__ ushort_t f2bf(float f) {
  __hip_bfloat16 h = __float2bfloat16(f);  // RNE
  union { __hip_bfloat16 h; ushort_t u; } v;
  v.h = h;
  return v.u;
}

// ============================ CSR build ============================

__global__ __launch_bounds__(256)
void gk_count(const int* __restrict__ dst, int* __restrict__ cnt, int E) {
  int e = blockIdx.x * 256 + threadIdx.x;
  if (e < E) atomicAdd(&cnt[dst[e]], 1);
}

__global__ __launch_bounds__(256)
void gk_scan1(const int* __restrict__ cnt, int* __restrict__ off,
              int* __restrict__ bsum, int n) {
  __shared__ int sm[256];
  int t = threadIdx.x;
  int base = blockIdx.x * 1024 + t * 4;
  int v0 = (base + 0 < n) ? cnt[base + 0] : 0;
  int v1 = (base + 1 < n) ? cnt[base + 1] : 0;
  int v2 = (base + 2 < n) ? cnt[base + 2] : 0;
  int v3 = (base + 3 < n) ? cnt[base + 3] : 0;
  int loc = v0 + v1 + v2 + v3;
  sm[t] = loc;
  __syncthreads();
  for (int o = 1; o < 256; o <<= 1) {
    int x = (t >= o) ? sm[t - o] : 0;
    __syncthreads();
    sm[t] += x;
    __syncthreads();
  }
  int run = sm[t] - loc;
  if (base + 0 < n) off[base + 0] = run;
  run += v0;
  if (base + 1 < n) off[base + 1] = run;
  run += v1;
  if (base + 2 < n) off[base + 2] = run;
  run += v2;
  if (base + 3 < n) off[base + 3] = run;
  if (t == 255) bsum[blockIdx.x] = sm[255];
}

__global__ __launch_bounds__(256)
void gk_scan2(int* __restrict__ bsum, int nb) {
  __shared__ int sm[256];
  int t = threadIdx.x;
  int v = (t < nb) ? bsum[t] : 0;
  sm[t] = v;
  __syncthreads();
  for (int o = 1; o < 256; o <<= 1) {
    int x = (t >= o) ? sm[t - o] : 0;
    __syncthreads();
    sm[t] += x;
    __syncthreads();
  }
  if (t < nb) bsum[t] = sm[t] - v;
}

__global__ __launch_bounds__(256)
void gk_scan3(int* __restrict__ off, const int* __restrict__ bsum, int n, int E) {
  int i = blockIdx.x * 256 + threadIdx.x;
  if (i < n) off[i] += bsum[i >> 10];
  if (i == 0) off[n] = E;
}

__global__ __launch_bounds__(256)
void gk_copy(int* __restrict__ d, const int* __restrict__ s, int n) {
  int i = blockIdx.x * 256 + threadIdx.x;
  if (i < n) d[i] = s[i];
}

__global__ __launch_bounds__(256)
void gk_fill(const int* __restrict__ src, const int* __restrict__ dst,
             int* __restrict__ cur, int* __restrict__ csr, int E) {
  int e = blockIdx.x * 256 + threadIdx.x;
  if (e < E) {
    int d = dst[e];
    int pos = atomicAdd(&cur[d], 1);
    csr[pos] = src[e];
  }
}

__global__ __launch_bounds__(256)
void gk_dinv(const int* __restrict__ off, float* __restrict__ dinv, int n) {
  int i = blockIdx.x * 256 + threadIdx.x;
  if (i < n) dinv[i] = rsqrtf((float)(off[i + 1] - off[i] + 1));
}

// ============================ encoders ============================

__global__ __launch_bounds__(128)
void gk_ligenc(const int* __restrict__ lig_x, const int* __restrict__ offs,
               const float* __restrict__ emb, ushort_t* __restrict__ A) {
  __shared__ int idx[9];
  int i = blockIdx.x;
  int c = threadIdx.x;
  if (c < 9) idx[c] = lig_x[i * 9 + c] + offs[c];
  __syncthreads();
  float acc = 0.f;
#pragma unroll
  for (int f = 0; f < 9; ++f) acc += emb[(size_t)idx[f] * EMB + c];
  A[(size_t)i * EMB + c] = f2bf(acc);
}

// prep: W[199,128] fp32 -> W^T bf16 [128 cols][224 k], K zero-padded.
__global__ __launch_bounds__(256)
void gk_recw2(const float* __restrict__ W, ushort_t* __restrict__ Wt) {
  int idx = blockIdx.x * 256 + threadIdx.x;  // 128*224 = 28672 total
  if (idx < 128 * 224) {
    int c = idx / 224, k = idx - c * 224;
    Wt[idx] = (k < 199) ? f2bf(W[(size_t)k * 128 + c]) : (ushort_t)0;
  }
}

// streaming fp32 -> bf16 cast of X[262144][199] into row-padded [262144][200]
__global__ __launch_bounds__(256)
void gk_xcast(const float* __restrict__ X, ushort_t* __restrict__ Xb) {
  const int ITEMS = NREC * 25;  // 25 chunks of 8 bf16 per row
  int stride = gridDim.x * 256;
  for (int v = blockIdx.x * 256 + threadIdx.x; v < ITEMS; v += stride) {
    int row = v / 25, sub = v - row * 25;
    int k0 = sub * 8;
    const float* xr = X + (size_t)row * 199 + k0;
    ushort_t tmp[8];
#pragma unroll
    for (int j = 0; j < 8; ++j) {
      float f = (k0 + j < 199) ? xr[j] : 0.f;
      tmp[j] = f2bf(f);
    }
    *(uint4*)(Xb + (size_t)row * 200 + k0) = *(uint4*)tmp;
  }
}

// rec encoder GEMM, LDS-free / barrier-free (verified round 3):
__global__ __launch_bounds__(256)
void gk_recenc2(const ushort_t* __restrict__ Xb, const int* __restrict__ xi,
                const float* __restrict__ emb1, const ushort_t* __restrict__ Wt,
                const float* __restrict__ b, ushort_t* __restrict__ A) {
  int t = threadIdx.x;
  int row0 = blockIdx.x * 128;
  int w = t >> 6, lane = t & 63;
  int m = lane & 15, quad = lane >> 4;
  int rbase = w * 32;
  int rA = row0 + rbase + m;
  int rB = rA + 16;

  f32x4 acc[2][8];
#pragma unroll
  for (int rt = 0; rt < 2; ++rt)
#pragma unroll
    for (int ct = 0; ct < 8; ++ct) acc[rt][ct] = (f32x4){0.f, 0.f, 0.f, 0.f};

  const ushort_t* xpA = Xb + (size_t)rA * 200 + quad * 8;
  const ushort_t* xpB = Xb + (size_t)rB * 200 + quad * 8;
  const ushort_t* wp = Wt + (size_t)m * 224 + quad * 8;

  for (int ch = 0; ch < 7; ++ch) {
    bf16x8 a0 = *(const bf16x8*)(xpA + ch * 32);
    bf16x8 a1 = *(const bf16x8*)(xpB + ch * 32);
#pragma unroll
    for (int ct = 0; ct < 8; ++ct) {
      bf16x8 bb = *(const bf16x8*)(wp + (size_t)ct * 16 * 224 + ch * 32);
      acc[0][ct] = __builtin_amdgcn_mfma_f32_16x16x32_bf16(a0, bb, acc[0][ct], 0, 0, 0);
      acc[1][ct] = __builtin_amdgcn_mfma_f32_16x16x32_bf16(a1, bb, acc[1][ct], 0, 0, 0);
    }
  }

  float bcol[8];
#pragma unroll
  for (int ct = 0; ct < 8; ++ct) bcol[ct] = b[ct * 16 + m];
#pragma unroll
  for (int rt = 0; rt < 2; ++rt) {
    int rb = row0 + rbase + rt * 16 + quad * 4;
#pragma unroll
    for (int rr = 0; rr < 4; ++rr) {
      int row = rb + rr;
      const float* e = emb1 + (size_t)xi[row] * 128;
#pragma unroll
      for (int ct = 0; ct < 8; ++ct) {
        int c = ct * 16 + m;
        float v = acc[rt][ct][rr] + bcol[ct] + e[c];
        A[(size_t)row * 128 + c] = f2bf(v);
      }
    }
  }
}

// ======================= per-layer prep =======================
__global__ __launch_bounds__(256)
void gk_prep(const float* __restrict__ W, const float* __restrict__ stats,
             const float* __restrict__ gamma, const float* __restrict__ beta,
             float inv_n, int donorm, ushort_t* __restrict__ Wt,
             float* __restrict__ bnscl, float* __restrict__ bnsh) {
  int idx = blockIdx.x * 256 + threadIdx.x;
  if (idx < 128) {
    if (donorm) {
      float mu = stats[idx] * inv_n;
      float var = stats[128 + idx] * inv_n - mu * mu;
      float s = gamma[idx] * rsqrtf(var + BN_EPS);
      bnscl[idx] = s;
      bnsh[idx] = beta[idx] - mu * s;
    } else {
      bnscl[idx] = 1.f;
      bnsh[idx] = 0.f;
    }
  }
  int c = idx >> 7, k = idx & 127;
  Wt[(size_t)c * 128 + k] = f2bf(W[(size_t)k * 128 + c]);
}

// ====================== MFMA GCN GEMM (verified) ======================
__global__ __launch_bounds__(256)
void gk_mm(const ushort_t* __restrict__ Xb, const ushort_t* __restrict__ Wt,
           const float* __restrict__ bnscl, const float* __restrict__ bnsh,
           int donorm, const float* __restrict__ dinv,
           ushort_t* __restrict__ gb) {
  __shared__ ushort_t Xs[128 * 128];
  __shared__ ushort_t Ws[128 * 128];
  int t = threadIdx.x;
  int row0 = blockIdx.x * 128;

  for (int i = t; i < 2048; i += 256) {
    int r = i >> 4, cc = i & 15;
    union { uint4 v; ushort_t s[8]; } u;
    u.v = *(const uint4*)(Xb + (size_t)(row0 + r) * 128 + cc * 8);
    if (donorm) {
#pragma unroll
      for (int j = 0; j < 8; ++j) {
        int k = cc * 8 + j;
        float f = fmaf(bf2f(u.s[j]), bnscl[k], bnsh[k]);
        f = f > 0.f ? f : 0.f;
        u.s[j] = f2bf(f);
      }
    }
    *(uint4*)&Xs[r * 128 + ((cc ^ (r & 15)) * 8)] = u.v;
  }
  for (int i = t; i < 2048; i += 256) {
    int c = i >> 4, cc = i & 15;
    uint4 u = *(const uint4*)(Wt + (size_t)c * 128 + cc * 8);
    *(uint4*)&Ws[c * 128 + ((cc ^ (c & 15)) * 8)] = u;
  }
  __syncthreads();

  int w = t >> 6, lane = t & 63;
  int m = lane & 15, quad = lane >> 4;
  int rbase = w * 32;

  f32x4 acc[2][8];
#pragma unroll
  for (int rt = 0; rt < 2; ++rt)
#pragma unroll
    for (int ct = 0; ct < 8; ++ct) acc[rt][ct] = (f32x4){0.f, 0.f, 0.f, 0.f};

#pragma unroll
  for (int kc8 = 0; kc8 < 16; kc8 += 4) {
    int ck = (kc8 + quad) ^ m;
    bf16x8 a0 = *(const bf16x8*)&Xs[(rbase + m) * 128 + ck * 8];
    bf16x8 a1 = *(const bf16x8*)&Xs[(rbase + 16 + m) * 128 + ck * 8];
#pragma unroll
    for (int ct = 0; ct < 8; ++ct) {
      bf16x8 b = *(const bf16x8*)&Ws[(ct * 16 + m) * 128 + ck * 8];
      acc[0][ct] = __builtin_amdgcn_mfma_f32_16x16x32_bf16(a0, b, acc[0][ct], 0, 0, 0);
      acc[1][ct] = __builtin_amdgcn_mfma_f32_16x16x32_bf16(a1, b, acc[1][ct], 0, 0, 0);
    }
  }

#pragma unroll
  for (int rt = 0; rt < 2; ++rt) {
    int rb = row0 + rbase + rt * 16 + quad * 4;
    float d0 = dinv[rb + 0], d1 = dinv[rb + 1];
    float d2 = dinv[rb + 2], d3 = dinv[rb + 3];
#pragma unroll
    for (int ct = 0; ct < 8; ++ct) {
      int c = ct * 16 + m;
      gb[(size_t)(rb + 0) * 128 + c] = f2bf(acc[rt][ct][0] * d0);
      gb[(size_t)(rb + 1) * 128 + c] = f2bf(acc[rt][ct][1] * d1);
      gb[(size_t)(rb + 2) * 128 + c] = f2bf(acc[rt][ct][2] * d2);
      gb[(size_t)(rb + 3) * 128 + c] = f2bf(acc[rt][ct][3] * d3);
    }
  }
}

// ---------------- aggregation v3 (full-width, used for ligand) ----------------

__device__ __forceinline__ void gather8(const ushort_t* __restrict__ g, int c0,
                                        int idxv, int q, unsigned int* v) {
#pragma unroll
  for (int k = 0; k < 8; ++k) {
    int idx = __shfl(idxv, q * 8 + k);
    v[k] = *(const unsigned int*)(g + (size_t)idx * 128 + c0);
  }
}

__device__ __forceinline__ void consume8(float2& acc, const unsigned int* v,
                                         int q, int deg) {
#pragma unroll
  for (int k = 0; k < 8; ++k) {
    float m = (q * 8 + k < deg) ? 1.f : 0.f;
    acc.x = fmaf(bf2f((ushort_t)(v[k] & 0xffffu)), m, acc.x);
    acc.y = fmaf(bf2f((ushort_t)(v[k] >> 16)), m, acc.y);
  }
}

__global__ __launch_bounds__(256)
void gk_agg(const ushort_t* __restrict__ g, const int* __restrict__ off,
            const int* __restrict__ csr, const float* __restrict__ dinv,
            ushort_t* __restrict__ outb, float* __restrict__ stats) {
  __shared__ float ls[128];
  __shared__ float lss[128];
  int t = threadIdx.x;
  int slot = t >> 6;        // 4 waves per block
  int lane = t & 63;
  int c0 = lane * 2;
  int i0 = blockIdx.x * 32;

  if (t < 128) { ls[t] = 0.f; lss[t] = 0.f; }
  __syncthreads();

  int offv = off[i0 + min(lane, 32)];

  int idxA[4], idxB[4], dAs[4], dBs[4];
#pragma unroll
  for (int p = 0; p < 4; ++p) {
    int base = slot * 2 + p * 8;
    int eA  = __shfl(offv, base + 0);
    int eB  = __shfl(offv, base + 1);
    int eB1 = __shfl(offv, base + 2);
    dAs[p] = eB - eA;
    dBs[p] = eB1 - eB;
    int adrA = (dAs[p] > 0) ? min(eA + lane, eB - 1) : 0;
    int adrB = (dBs[p] > 0) ? min(eB + lane, eB1 - 1) : 0;
    idxA[p] = csr[adrA];
    idxB[p] = csr[adrB];
  }

  float sx = 0.f, sy = 0.f, ssx = 0.f, ssy = 0.f;

#pragma unroll
  for (int p = 0; p < 4; ++p) {
    int rA = i0 + slot * 2 + p * 8;
    int rB = rA + 1;
    int degA = dAs[p], degB = dBs[p];
    float dA = dinv[rA], dB = dinv[rB];

    unsigned int sU = *(const unsigned int*)(g + (size_t)rA * 128 + c0);
    unsigned int sV = *(const unsigned int*)(g + (size_t)rB * 128 + c0);
    float2 accA = make_float2(bf2f((ushort_t)(sU & 0xffffu)),
                              bf2f((ushort_t)(sU >> 16)));
    float2 accB = make_float2(bf2f((ushort_t)(sV & 0xffffu)),
                              bf2f((ushort_t)(sV >> 16)));

    int dAf = min(degA, 64), dBf = min(degB, 64);
    int nc = (max(dAf, dBf) + 7) >> 3;
    if (nc > 0) {
      unsigned int vA[8], vB[8];
      gather8(g, c0, idxA[p], 0, vA);
      gather8(g, c0, idxB[p], 0, vB);
      for (int q = 1; q < nc; ++q) {
        unsigned int wA[8], wB[8];
        gather8(g, c0, idxA[p], q, wA);
        gather8(g, c0, idxB[p], q, wB);
        consume8(accA, vA, q - 1, dAf);
        consume8(accB, vB, q - 1, dBf);
#pragma unroll
        for (int k = 0; k < 8; ++k) { vA[k] = wA[k]; vB[k] = wB[k]; }
      }
      consume8(accA, vA, nc - 1, dAf);
      consume8(accB, vB, nc - 1, dBf);
    }

    if (degA > 64) {
      int eA = __shfl(offv, slot * 2 + p * 8);
      for (int e = eA + 64; e < eA + degA; ++e) {
        int idx = csr[e];
        unsigned int v = *(const unsigned int*)(g + (size_t)idx * 128 + c0);
        accA.x += bf2f((ushort_t)(v & 0xffffu));
        accA.y += bf2f((ushort_t)(v >> 16));
      }
    }
    if (degB > 64) {
      int eB = __shfl(offv, slot * 2 + p * 8 + 1);
      for (int e = eB + 64; e < eB + degB; ++e) {
        int idx = csr[e];
        unsigned int v = *(const unsigned int*)(g + (size_t)idx * 128 + c0);
        accB.x += bf2f((ushort_t)(v & 0xffffu));
        accB.y += bf2f((ushort_t)(v >> 16));
      }
    }

    accA.x *= dA; accA.y *= dA;
    accB.x *= dB; accB.y *= dB;
    unsigned int oA = (unsigned int)f2bf(accA.x) | ((unsigned int)f2bf(accA.y) << 16);
    unsigned int oB = (unsigned int)f2bf(accB.x) | ((unsigned int)f2bf(accB.y) << 16);
    *(unsigned int*)(outb + (size_t)rA * 128 + c0) = oA;
    *(unsigned int*)(outb + (size_t)rB * 128 + c0) = oB;
    sx += accA.x + accB.x;
    sy += accA.y + accB.y;
    ssx = fmaf(accA.x, accA.x, ssx); ssx = fmaf(accB.x, accB.x, ssx);
    ssy = fmaf(accA.y, accA.y, ssy); ssy = fmaf(accB.y, accB.y, ssy);
  }

  atomicAdd(&ls[c0 + 0], sx);
  atomicAdd(&ls[c0 + 1], sy);
  atomicAdd(&lss[c0 + 0], ssx);
  atomicAdd(&lss[c0 + 1], ssy);
  __syncthreads();
  if (t < 128) {
    atomicAdd(&stats[t], ls[t]);
    atomicAdd(&stats[t + 128], lss[t]);
  }
}

// ---------------- aggregation v4: column-split (rec path) ----------------
// Two sequential passes over columns [0,64) and [64,128). Halves the L3
// working set of the random gather (thrash fix). Half-wave pairing: lanes
// 0-31 own row rA's 64 cols, lanes 32-63 own row rB's -> each gather instr
// still moves 256B. csr indices hoisted: one coalesced load covers both
// rows' first 32 edges, distributed via __shfl. deg>32 scalar tail (rare).

__device__ __forceinline__ void gatherc(const ushort_t* __restrict__ g, int c,
                                        int idxv, int q, int hbase,
                                        unsigned int* v) {
#pragma unroll
  for (int k = 0; k < 8; ++k) {
    int idx = __shfl(idxv, hbase + q * 8 + k);
    v[k] = *(const unsigned int*)(g + (size_t)idx * 128 + c);
  }
}

__device__ __forceinline__ void consumec(float& ax, float& ay,
                                         const unsigned int* v, int q, int dc) {
#pragma unroll
  for (int k = 0; k < 8; ++k) {
    float m = (q * 8 + k < dc) ? 1.f : 0.f;
    ax = fmaf(bf2f((ushort_t)(v[k] & 0xffffu)), m, ax);
    ay = fmaf(bf2f((ushort_t)(v[k] >> 16)), m, ay);
  }
}

__global__ __launch_bounds__(256)
void gk_aggc(const ushort_t* __restrict__ g, const int* __restrict__ off,
             const int* __restrict__ csr, const float* __restrict__ dinv,
             ushort_t* __restrict__ outb, float* __restrict__ stats, int col0) {
  __shared__ float ls[64];
  __shared__ float lss[64];
  int t = threadIdx.x;
  int w = t >> 6, lane = t & 63;
  int h = lane >> 5, sl = lane & 31;
  int hbase = h * 32;
  int c = col0 + sl * 2;
  int i0 = blockIdx.x * 32;

  if (t < 64) { ls[t] = 0.f; lss[t] = 0.f; }
  __syncthreads();

  int offv = off[i0 + min(lane, 32)];

  int idxP[4], degS[4], eS[4], ncw[4];
#pragma unroll
  for (int p = 0; p < 4; ++p) {
    int rb = w * 8 + 2 * p;
    int eA  = __shfl(offv, rb);
    int eM  = __shfl(offv, rb + 1);
    int eB1 = __shfl(offv, rb + 2);
    int dA = eM - eA, dB = eB1 - eM;
    ncw[p] = (min(max(dA, dB), 32) + 7) >> 3;
    int d = h ? dB : dA;
    int e0 = h ? eM : eA;
    degS[p] = d;
    eS[p] = e0;
    int adr = (d > 0) ? (e0 + min(sl, d - 1)) : 0;
    idxP[p] = csr[adr];
  }

  float sx = 0.f, sy = 0.f, ssx = 0.f, ssy = 0.f;

#pragma unroll
  for (int p = 0; p < 4; ++p) {
    int row = i0 + w * 8 + 2 * p + h;
    int d = degS[p];
    int dc = min(d, 32);
    float dv = dinv[row];
    unsigned int su = *(const unsigned int*)(g + (size_t)row * 128 + c);
    float ax = bf2f((ushort_t)(su & 0xffffu));
    float ay = bf2f((ushort_t)(su >> 16));

    int nc = ncw[p];
    if (nc > 0) {
      unsigned int v[8];
      gatherc(g, c, idxP[p], 0, hbase, v);
      for (int q = 1; q < nc; ++q) {
        unsigned int nv[8];
        gatherc(g, c, idxP[p], q, hbase, nv);
        consumec(ax, ay, v, q - 1, dc);
#pragma unroll
        for (int k = 0; k < 8; ++k) v[k] = nv[k];
      }
      consumec(ax, ay, v, nc - 1, dc);
    }
    if (d > 32) {  // rare tail
      for (int e = eS[p] + 32; e < eS[p] + d; ++e) {
        int idx = csr[e];
        unsigned int vv = *(const unsigned int*)(g + (size_t)idx * 128 + c);
        ax += bf2f((ushort_t)(vv & 0xffffu));
        ay += bf2f((ushort_t)(vv >> 16));
      }
    }

    ax *= dv; ay *= dv;
    unsigned int o = (unsigned int)f2bf(ax) | ((unsigned int)f2bf(ay) << 16);
    *(unsigned int*)(outb + (size_t)row * 128 + c) = o;
    sx += ax; sy += ay;
    ssx = fmaf(ax, ax, ssx);
    ssy = fmaf(ay, ay, ssy);
  }

  atomicAdd(&ls[sl * 2 + 0], sx);
  atomicAdd(&ls[sl * 2 + 1], sy);
  atomicAdd(&lss[sl * 2 + 0], ssx);
  atomicAdd(&lss[sl * 2 + 1], ssy);
  __syncthreads();
  if (t < 64) {
    atomicAdd(&stats[col0 + t], ls[t]);
    atomicAdd(&stats[128 + col0 + t], lss[t]);
  }
}

// per-graph mean of relu(bn(A_bf)) for the last layer
__global__ __launch_bounds__(128)
void gk_pool(const ushort_t* __restrict__ A, const float* __restrict__ stats,
             const float* __restrict__ gamma, const float* __restrict__ beta,
             float inv_n, float* __restrict__ z, int npg, int zoff) {
  int gidx = blockIdx.x;
  int c = threadIdx.x;
  float mu = stats[c] * inv_n;
  float var = stats[128 + c] * inv_n - mu * mu;
  float scl = gamma[c] * rsqrtf(var + BN_EPS);
  float be = beta[c];
  float sum = 0.f;
  int r0 = gidx * npg;
  for (int r = 0; r < npg; ++r) {
    float v = (bf2f(A[(size_t)(r0 + r) * 128 + c]) - mu) * scl + be;
    sum += v > 0.f ? v : 0.f;
  }
  z[(size_t)gidx * 256 + zoff + c] = sum * (1.0f / (float)npg);
}

__global__ __launch_bounds__(128)
void gk_mlp(const float* __restrict__ z, const float* __restrict__ w1,
            const float* __restrict__ b1, const float* __restrict__ w2,
            const float* __restrict__ b2, float* __restrict__ out) {
  __shared__ float zs[256];
  __shared__ float red[128];
  int gidx = blockIdx.x, t = threadIdx.x;
  zs[t] = z[(size_t)gidx * 256 + t];
  zs[t + 128] = z[(size_t)gidx * 256 + 128 + t];
  __syncthreads();
  float acc = b1[t];
  for (int k = 0; k < 256; ++k) acc += zs[k] * w1[(size_t)k * 128 + t];
  acc = (acc > 0.f ? acc : 0.f) * w2[t];
  red[t] = acc;
  __syncthreads();
  for (int o = 64; o > 0; o >>= 1) {
    if (t < o) red[t] += red[t + o];
    __syncthreads();
  }
  if (t == 0) out[gidx] = red[0] + b2[0];
}

// ============================ launch ============================

extern "C" void kernel_launch(void* const* d_in, const int* in_sizes, int n_in,
                              void* d_out, int out_size, void* d_ws, size_t ws_size,
                              hipStream_t stream) {
  (void)in_sizes; (void)n_in; (void)out_size; (void)ws_size;
  const int*   lig_x       = (const int*)  d_in[0];
  const int*   rec_x_int   = (const int*)  d_in[1];
  const float* rec_x_float = (const float*)d_in[2];
  const int*   lig_ei      = (const int*)  d_in[3];
  const int*   rec_ei      = (const int*)  d_in[4];
  const int*   atom_off    = (const int*)  d_in[7];
  const float* atom_emb    = (const float*)d_in[8];
  const float* rec_emb1    = (const float*)d_in[9];
  const float* rec_w       = (const float*)d_in[10];
  const float* rec_b       = (const float*)d_in[11];
  const float* lig_W       = (const float*)d_in[12];
  const float* lig_gamma   = (const float*)d_in[14];
  const float* lig_beta    = (const float*)d_in[15];
  const float* rec_W       = (const float*)d_in[16];
  const float* rec_gamma   = (const float*)d_in[18];
  const float* rec_beta    = (const float*)d_in[19];
  const float* out_w1      = (const float*)d_in[20];
  const float* out_b1      = (const float*)d_in[21];
  const float* out_w2      = (const float*)d_in[22];
  const float* out_b2      = (const float*)d_in[23];
  float* out = (float*)d_out;

  char* p = (char*)d_ws;
  auto alloc = [&](size_t bytes) -> void* {
    void* r = p;
    p += (bytes + 255) & ~(size_t)255;
    return r;
  };
  ushort_t* Ab     = (ushort_t*)alloc((size_t)NREC * EMB * 2);  // features bf16
  ushort_t* Gb     = (ushort_t*)alloc((size_t)NREC * EMB * 2);  // g bf16
  ushort_t* Wtb    = (ushort_t*)alloc((size_t)EMB * EMB * 2);   // W^T bf16
  ushort_t* WtK    = (ushort_t*)alloc((size_t)EMB * 224 * 2);   // rec_w^T bf16, K-padded
  ushort_t* Xb2    = (ushort_t*)alloc(((size_t)NREC * 200 + 64) * 2);  // bf16 X, padded rows
  float* bnscl     = (float*)alloc(128 * 4);
  float* bnsh      = (float*)alloc(128 * 4);
  float* dinv_lig  = (float*)alloc((size_t)NLIG * 4);
  float* dinv_rec  = (float*)alloc((size_t)NREC * 4);
  int*   cnt_lig   = (int*)  alloc((size_t)NLIG * 4);
  int*   cnt_rec   = (int*)  alloc((size_t)NREC * 4);
  int*   off_lig   = (int*)  alloc((size_t)(NLIG + 8) * 4);
  int*   off_rec   = (int*)  alloc((size_t)(NREC + 8) * 4);
  int*   csr_lig   = (int*)  alloc((size_t)ELIG * 4);
  int*   csr_rec   = (int*)  alloc((size_t)EREC * 4);
  int*   bsum_lig  = (int*)  alloc(256 * 4);
  int*   bsum_rec  = (int*)  alloc(256 * 4);
  float* stats     = (float*)alloc(256 * 4);
  float* z         = (float*)alloc((size_t)NGRAPH * 256 * 4);

  // ---- CSR build ----
  hipMemsetAsync(cnt_lig, 0, (size_t)NLIG * 4, stream);
  hipMemsetAsync(cnt_rec, 0, (size_t)NREC * 4, stream);
  gk_count<<<ELIG / 256, 256, 0, stream>>>(lig_ei + ELIG, cnt_lig, ELIG);
  gk_count<<<EREC / 256, 256, 0, stream>>>(rec_ei + EREC, cnt_rec, EREC);
  gk_scan1<<<NLIG / 1024, 256, 0, stream>>>(cnt_lig, off_lig, bsum_lig, NLIG);
  gk_scan2<<<1, 256, 0, stream>>>(bsum_lig, NLIG / 1024);
  gk_scan3<<<NLIG / 256, 256, 0, stream>>>(off_lig, bsum_lig, NLIG, ELIG);
  gk_scan1<<<NREC / 1024, 256, 0, stream>>>(cnt_rec, off_rec, bsum_rec, NREC);
  gk_scan2<<<1, 256, 0, stream>>>(bsum_rec, NREC / 1024);
  gk_scan3<<<NREC / 256, 256, 0, stream>>>(off_rec, bsum_rec, NREC, EREC);
  gk_copy<<<NLIG / 256, 256, 0, stream>>>(cnt_lig, off_lig, NLIG);
  gk_copy<<<NREC / 256, 256, 0, stream>>>(cnt_rec, off_rec, NREC);
  gk_fill<<<ELIG / 256, 256, 0, stream>>>(lig_ei, lig_ei + ELIG, cnt_lig, csr_lig, ELIG);
  gk_fill<<<EREC / 256, 256, 0, stream>>>(rec_ei, rec_ei + EREC, cnt_rec, csr_rec, EREC);
  gk_dinv<<<NLIG / 256, 256, 0, stream>>>(off_lig, dinv_lig, NLIG);
  gk_dinv<<<NREC / 256, 256, 0, stream>>>(off_rec, dinv_rec, NREC);

  auto run_entity = [&](const float* Wall, const float* gamma, const float* beta,
                        const int* offv, const int* csrv, const float* dinv,
                        int n, int npg, int zoff, int colsplit) {
    float inv_n = 1.0f / (float)n;
    for (int l = 0; l < 3; ++l) {
      const float* W = Wall + (size_t)l * EMB * EMB;
      const float* gm = (l > 0) ? gamma + (size_t)(l - 1) * EMB : gamma;
      const float* bt = (l > 0) ? beta + (size_t)(l - 1) * EMB : beta;
      gk_prep<<<64, 256, 0, stream>>>(W, stats, gm, bt, inv_n, l > 0 ? 1 : 0,
                                      Wtb, bnscl, bnsh);
      hipMemsetAsync(stats, 0, 256 * 4, stream);
      gk_mm<<<n / 128, 256, 0, stream>>>(Ab, Wtb, bnscl, bnsh, l > 0 ? 1 : 0,
                                         dinv, Gb);
      if (colsplit) {
        gk_aggc<<<n / 32, 256, 0, stream>>>(Gb, offv, csrv, dinv, Ab, stats, 0);
        gk_aggc<<<n / 32, 256, 0, stream>>>(Gb, offv, csrv, dinv, Ab, stats, 64);
      } else {
        gk_agg<<<n / 32, 256, 0, stream>>>(Gb, offv, csrv, dinv, Ab, stats);
      }
    }
    gk_pool<<<NGRAPH, 128, 0, stream>>>(Ab, stats, gamma + 2 * EMB, beta + 2 * EMB,
                                        inv_n, z, npg, zoff);
  };

  // ---- ligand path ----
  gk_ligenc<<<NLIG, 128, 0, stream>>>(lig_x, atom_off, atom_emb, Ab);
  run_entity(lig_W, lig_gamma, lig_beta, off_lig, csr_lig, dinv_lig,
             NLIG, NLIG / NGRAPH, 0, 0);

  // ---- receptor path ----
  gk_recw2<<<112, 256, 0, stream>>>(rec_w, WtK);
  gk_xcast<<<2048, 256, 0, stream>>>(rec_x_float, Xb2);
  gk_recenc2<<<NREC / 128, 256, 0, stream>>>(Xb2, rec_x_int, rec_emb1,
                                             WtK, rec_b, Ab);
  run_entity(rec_W, rec_gamma, rec_beta, off_rec, csr_rec, dinv_rec,
             NREC, NREC / NGRAPH, EMB, 1);

  // ---- head ----
  gk_mlp<<<NGRAPH, 128, 0, stream>>>(z, out_w1, out_b1, out_w2, out_b2, out);
}

// Round 7
// 1794.566 us; speedup vs baseline: 1.3632x; 1.3632x over previous
//
#include <hip/hip_runtime.h>
#include <hip/hip_bf16.h>
#include <cstdint>
#include <cstddef>

#define EMB 128
#define NLIG 32768
#define NREC 262144
#define NGRAPH 1024
#define ELIG 327680
#define EREC 2097152
#define BN_EPS 1e-5f

typedef unsigned short ushort_t;
typedef short bf16x8 __attribute__((ext_vector_type(8)));
typedef float f32x4 __attribute__((ext_vector_type(4)));

__device__ __forceinline__ float bf2f(ushort_t u) {
  union { unsigned int i; float f; } v;
  v.i = ((unsigned int)u) << 16;
  return v.f;
}
__device__ __forceinline__ ushort_t f2bf(float f) {
  __hip_bfloat16 h = __float2bfloat16(f);  // RNE
  union { __hip_bfloat16 h; ushort_t u; } v;
  v.h = h;
  return v.u;
}

// ============================ CSR build ============================

__global__ __launch_bounds__(256)
void gk_count(const int* __restrict__ dst, int* __restrict__ cnt, int E) {
  int e = blockIdx.x * 256 + threadIdx.x;
  if (e < E) atomicAdd(&cnt[dst[e]], 1);
}

__global__ __launch_bounds__(256)
void gk_scan1(const int* __restrict__ cnt, int* __restrict__ off,
              int* __restrict__ bsum, int n) {
  __shared__ int sm[256];
  int t = threadIdx.x;
  int base = blockIdx.x * 1024 + t * 4;
  int v0 = (base + 0 < n) ? cnt[base + 0] : 0;
  int v1 = (base + 1 < n) ? cnt[base + 1] : 0;
  int v2 = (base + 2 < n) ? cnt[base + 2] : 0;
  int v3 = (base + 3 < n) ? cnt[base + 3] : 0;
  int loc = v0 + v1 + v2 + v3;
  sm[t] = loc;
  __syncthreads();
  for (int o = 1; o < 256; o <<= 1) {
    int x = (t >= o) ? sm[t - o] : 0;
    __syncthreads();
    sm[t] += x;
    __syncthreads();
  }
  int run = sm[t] - loc;
  if (base + 0 < n) off[base + 0] = run;
  run += v0;
  if (base + 1 < n) off[base + 1] = run;
  run += v1;
  if (base + 2 < n) off[base + 2] = run;
  run += v2;
  if (base + 3 < n) off[base + 3] = run;
  if (t == 255) bsum[blockIdx.x] = sm[255];
}

__global__ __launch_bounds__(256)
void gk_scan2(int* __restrict__ bsum, int nb) {
  __shared__ int sm[256];
  int t = threadIdx.x;
  int v = (t < nb) ? bsum[t] : 0;
  sm[t] = v;
  __syncthreads();
  for (int o = 1; o < 256; o <<= 1) {
    int x = (t >= o) ? sm[t - o] : 0;
    __syncthreads();
    sm[t] += x;
    __syncthreads();
  }
  if (t < nb) bsum[t] = sm[t] - v;
}

// scan3 fused: finalize off, init cur (=cnt array, overwritten after read),
// and compute dinv from the still-intact counts.
__global__ __launch_bounds__(256)
void gk_scan3f(int* __restrict__ off, const int* __restrict__ bsum,
               int* __restrict__ cur, float* __restrict__ dinv, int n, int E) {
  int i = blockIdx.x * 256 + threadIdx.x;
  if (i < n) {
    int deg = cur[i];                    // cnt value (pre-overwrite)
    int o = off[i] + bsum[i >> 10];
    off[i] = o;
    cur[i] = o;
    dinv[i] = rsqrtf((float)(deg + 1));
  }
  if (i == 0) off[n] = E;
}

__global__ __launch_bounds__(256)
void gk_fill(const int* __restrict__ src, const int* __restrict__ dst,
             int* __restrict__ cur, int* __restrict__ csr, int E) {
  int e = blockIdx.x * 256 + threadIdx.x;
  if (e < E) {
    int d = dst[e];
    int pos = atomicAdd(&cur[d], 1);
    csr[pos] = src[e];
  }
}

// ============================ encoder prep ============================

// prep: W[199,128] fp32 -> W^T bf16 [128 cols][224 k], K zero-padded.
__global__ __launch_bounds__(256)
void gk_recw2(const float* __restrict__ W, ushort_t* __restrict__ Wt) {
  int idx = blockIdx.x * 256 + threadIdx.x;  // 128*224 = 28672 total
  if (idx < 128 * 224) {
    int c = idx / 224, k = idx - c * 224;
    Wt[idx] = (k < 199) ? f2bf(W[(size_t)k * 128 + c]) : (ushort_t)0;
  }
}

// streaming fp32 -> bf16 cast of X[262144][199] into row-padded [262144][200]
__global__ __launch_bounds__(256)
void gk_xcast(const float* __restrict__ X, ushort_t* __restrict__ Xb) {
  const int ITEMS = NREC * 25;  // 25 chunks of 8 bf16 per row
  int stride = gridDim.x * 256;
  for (int v = blockIdx.x * 256 + threadIdx.x; v < ITEMS; v += stride) {
    int row = v / 25, sub = v - row * 25;
    int k0 = sub * 8;
    const float* xr = X + (size_t)row * 199 + k0;
    ushort_t tmp[8];
#pragma unroll
    for (int j = 0; j < 8; ++j) {
      float f = (k0 + j < 199) ? xr[j] : 0.f;
      tmp[j] = f2bf(f);
    }
    *(uint4*)(Xb + (size_t)row * 200 + k0) = *(uint4*)tmp;
  }
}

// ============== fused encoders: lig (2 nodes/block) + rec MFMA GEMM ==============
// blocks [0, NLIG/2): ligand embedding-sum encoder.
// blocks [NLIG/2, NLIG/2+NREC/128): recenc2 (verified round 3) verbatim.
#define LIGB (NLIG / 2)
__global__ __launch_bounds__(256)
void gk_enc2(const int* __restrict__ lig_x, const int* __restrict__ offs,
             const float* __restrict__ emb,
             const ushort_t* __restrict__ Xb, const int* __restrict__ xi,
             const float* __restrict__ emb1, const ushort_t* __restrict__ Wt,
             const float* __restrict__ b,
             ushort_t* __restrict__ Al, ushort_t* __restrict__ Ar) {
  int t = threadIdx.x;
  if (blockIdx.x < LIGB) {
    __shared__ int idx[2][9];
    int n0 = blockIdx.x * 2;
    if (t < 9) idx[0][t] = lig_x[n0 * 9 + t] + offs[t];
    else if (t >= 128 && t < 137) idx[1][t - 128] = lig_x[(n0 + 1) * 9 + (t - 128)] + offs[t - 128];
    __syncthreads();
    int half = t >> 7, c = t & 127;
    float acc = 0.f;
#pragma unroll
    for (int f = 0; f < 9; ++f) acc += emb[(size_t)idx[half][f] * EMB + c];
    Al[(size_t)(n0 + half) * EMB + c] = f2bf(acc);
    return;
  }
  // ---- rec encoder (LDS-free / barrier-free), verbatim ----
  int row0 = (blockIdx.x - LIGB) * 128;
  int w = t >> 6, lane = t & 63;
  int m = lane & 15, quad = lane >> 4;
  int rbase = w * 32;
  int rA = row0 + rbase + m;
  int rB = rA + 16;

  f32x4 acc[2][8];
#pragma unroll
  for (int rt = 0; rt < 2; ++rt)
#pragma unroll
    for (int ct = 0; ct < 8; ++ct) acc[rt][ct] = (f32x4){0.f, 0.f, 0.f, 0.f};

  const ushort_t* xpA = Xb + (size_t)rA * 200 + quad * 8;
  const ushort_t* xpB = Xb + (size_t)rB * 200 + quad * 8;
  const ushort_t* wp = Wt + (size_t)m * 224 + quad * 8;

  for (int ch = 0; ch < 7; ++ch) {
    bf16x8 a0 = *(const bf16x8*)(xpA + ch * 32);
    bf16x8 a1 = *(const bf16x8*)(xpB + ch * 32);
#pragma unroll
    for (int ct = 0; ct < 8; ++ct) {
      bf16x8 bb = *(const bf16x8*)(wp + (size_t)ct * 16 * 224 + ch * 32);
      acc[0][ct] = __builtin_amdgcn_mfma_f32_16x16x32_bf16(a0, bb, acc[0][ct], 0, 0, 0);
      acc[1][ct] = __builtin_amdgcn_mfma_f32_16x16x32_bf16(a1, bb, acc[1][ct], 0, 0, 0);
    }
  }

  float bcol[8];
#pragma unroll
  for (int ct = 0; ct < 8; ++ct) bcol[ct] = b[ct * 16 + m];
#pragma unroll
  for (int rt = 0; rt < 2; ++rt) {
    int rb = row0 + rbase + rt * 16 + quad * 4;
#pragma unroll
    for (int rr = 0; rr < 4; ++rr) {
      int row = rb + rr;
      const float* e = emb1 + (size_t)xi[row] * 128;
#pragma unroll
      for (int ct = 0; ct < 8; ++ct) {
        int c = ct * 16 + m;
        float v = acc[rt][ct][rr] + bcol[ct] + e[c];
        Ar[(size_t)row * 128 + c] = f2bf(v);
      }
    }
  }
}

// ======================= fused per-layer prep (both entities) =======================
__global__ __launch_bounds__(256)
void gk_prep2(const float* __restrict__ Wl, const float* __restrict__ Wr,
              const float* __restrict__ statsAll,
              const float* __restrict__ gml, const float* __restrict__ btl,
              const float* __restrict__ gmr, const float* __restrict__ btr,
              int donorm,
              ushort_t* __restrict__ Wtl, ushort_t* __restrict__ Wtr,
              float* __restrict__ scll, float* __restrict__ shl,
              float* __restrict__ sclr, float* __restrict__ shr) {
  int bidx = blockIdx.x;
  bool isl = bidx < 64;
  const float* W = isl ? Wl : Wr;
  const float* stats = statsAll + (isl ? 0 : 256);
  const float* gamma = isl ? gml : gmr;
  const float* beta = isl ? btl : btr;
  float inv_n = isl ? (1.f / (float)NLIG) : (1.f / (float)NREC);
  ushort_t* Wt = isl ? Wtl : Wtr;
  float* bnscl = isl ? scll : sclr;
  float* bnsh = isl ? shl : shr;
  int idx = (isl ? bidx : bidx - 64) * 256 + threadIdx.x;
  if (idx < 128) {
    if (donorm) {
      float mu = stats[idx] * inv_n;
      float var = stats[128 + idx] * inv_n - mu * mu;
      float s = gamma[idx] * rsqrtf(var + BN_EPS);
      bnscl[idx] = s;
      bnsh[idx] = beta[idx] - mu * s;
    } else {
      bnscl[idx] = 1.f;
      bnsh[idx] = 0.f;
    }
  }
  int c = idx >> 7, k = idx & 127;
  Wt[(size_t)c * 128 + k] = f2bf(W[(size_t)k * 128 + c]);
}

// ====================== fused MFMA GCN GEMM (both entities) ======================
#define MMB_L (NLIG / 128)
__global__ __launch_bounds__(256)
void gk_mm2(const ushort_t* __restrict__ Xl, const ushort_t* __restrict__ Xr,
            const ushort_t* __restrict__ Wtl, const ushort_t* __restrict__ Wtr,
            const float* __restrict__ scll, const float* __restrict__ shl,
            const float* __restrict__ sclr, const float* __restrict__ shr,
            int donorm,
            const float* __restrict__ dinvl, const float* __restrict__ dinvr,
            ushort_t* __restrict__ gbl, ushort_t* __restrict__ gbr) {
  bool isl = blockIdx.x < MMB_L;
  const ushort_t* Xb = isl ? Xl : Xr;
  const ushort_t* Wt = isl ? Wtl : Wtr;
  const float* bnscl = isl ? scll : sclr;
  const float* bnsh = isl ? shl : shr;
  const float* dinv = isl ? dinvl : dinvr;
  ushort_t* gb = isl ? gbl : gbr;
  int row0 = (isl ? blockIdx.x : blockIdx.x - MMB_L) * 128;

  __shared__ ushort_t Xs[128 * 128];
  __shared__ ushort_t Ws[128 * 128];
  int t = threadIdx.x;

  for (int i = t; i < 2048; i += 256) {
    int r = i >> 4, cc = i & 15;
    union { uint4 v; ushort_t s[8]; } u;
    u.v = *(const uint4*)(Xb + (size_t)(row0 + r) * 128 + cc * 8);
    if (donorm) {
#pragma unroll
      for (int j = 0; j < 8; ++j) {
        int k = cc * 8 + j;
        float f = fmaf(bf2f(u.s[j]), bnscl[k], bnsh[k]);
        f = f > 0.f ? f : 0.f;
        u.s[j] = f2bf(f);
      }
    }
    *(uint4*)&Xs[r * 128 + ((cc ^ (r & 15)) * 8)] = u.v;
  }
  for (int i = t; i < 2048; i += 256) {
    int c = i >> 4, cc = i & 15;
    uint4 u = *(const uint4*)(Wt + (size_t)c * 128 + cc * 8);
    *(uint4*)&Ws[c * 128 + ((cc ^ (c & 15)) * 8)] = u;
  }
  __syncthreads();

  int w = t >> 6, lane = t & 63;
  int m = lane & 15, quad = lane >> 4;
  int rbase = w * 32;

  f32x4 acc[2][8];
#pragma unroll
  for (int rt = 0; rt < 2; ++rt)
#pragma unroll
    for (int ct = 0; ct < 8; ++ct) acc[rt][ct] = (f32x4){0.f, 0.f, 0.f, 0.f};

#pragma unroll
  for (int kc8 = 0; kc8 < 16; kc8 += 4) {
    int ck = (kc8 + quad) ^ m;
    bf16x8 a0 = *(const bf16x8*)&Xs[(rbase + m) * 128 + ck * 8];
    bf16x8 a1 = *(const bf16x8*)&Xs[(rbase + 16 + m) * 128 + ck * 8];
#pragma unroll
    for (int ct = 0; ct < 8; ++ct) {
      bf16x8 b = *(const bf16x8*)&Ws[(ct * 16 + m) * 128 + ck * 8];
      acc[0][ct] = __builtin_amdgcn_mfma_f32_16x16x32_bf16(a0, b, acc[0][ct], 0, 0, 0);
      acc[1][ct] = __builtin_amdgcn_mfma_f32_16x16x32_bf16(a1, b, acc[1][ct], 0, 0, 0);
    }
  }

#pragma unroll
  for (int rt = 0; rt < 2; ++rt) {
    int rb = row0 + rbase + rt * 16 + quad * 4;
    float d0 = dinv[rb + 0], d1 = dinv[rb + 1];
    float d2 = dinv[rb + 2], d3 = dinv[rb + 3];
#pragma unroll
    for (int ct = 0; ct < 8; ++ct) {
      int c = ct * 16 + m;
      gb[(size_t)(rb + 0) * 128 + c] = f2bf(acc[rt][ct][0] * d0);
      gb[(size_t)(rb + 1) * 128 + c] = f2bf(acc[rt][ct][1] * d1);
      gb[(size_t)(rb + 2) * 128 + c] = f2bf(acc[rt][ct][2] * d2);
      gb[(size_t)(rb + 3) * 128 + c] = f2bf(acc[rt][ct][3] * d3);
    }
  }
}

// ---------------- fused aggregation (v3 body, both entities) ----------------

__device__ __forceinline__ void gather8(const ushort_t* __restrict__ g, int c0,
                                        int idxv, int q, unsigned int* v) {
#pragma unroll
  for (int k = 0; k < 8; ++k) {
    int idx = __shfl(idxv, q * 8 + k);
    v[k] = *(const unsigned int*)(g + (size_t)idx * 128 + c0);
  }
}

__device__ __forceinline__ void consume8(float2& acc, const unsigned int* v,
                                         int q, int deg) {
#pragma unroll
  for (int k = 0; k < 8; ++k) {
    float m = (q * 8 + k < deg) ? 1.f : 0.f;
    acc.x = fmaf(bf2f((ushort_t)(v[k] & 0xffffu)), m, acc.x);
    acc.y = fmaf(bf2f((ushort_t)(v[k] >> 16)), m, acc.y);
  }
}

#define AGB_L (NLIG / 32)
__global__ __launch_bounds__(256)
void gk_agg2(const ushort_t* __restrict__ gl, const ushort_t* __restrict__ gr,
             const int* __restrict__ offl, const int* __restrict__ offr,
             const int* __restrict__ csrl, const int* __restrict__ csrr,
             const float* __restrict__ dinvl, const float* __restrict__ dinvr,
             ushort_t* __restrict__ outl, ushort_t* __restrict__ outr,
             float* __restrict__ statsAll) {
  bool isl = blockIdx.x < AGB_L;
  const ushort_t* g = isl ? gl : gr;
  const int* off = isl ? offl : offr;
  const int* csr = isl ? csrl : csrr;
  const float* dinv = isl ? dinvl : dinvr;
  ushort_t* outb = isl ? outl : outr;
  float* stats = statsAll + (isl ? 0 : 256);
  int i0 = (isl ? blockIdx.x : blockIdx.x - AGB_L) * 32;

  __shared__ float ls[128];
  __shared__ float lss[128];
  int t = threadIdx.x;
  int slot = t >> 6;
  int lane = t & 63;
  int c0 = lane * 2;

  if (t < 128) { ls[t] = 0.f; lss[t] = 0.f; }
  __syncthreads();

  int offv = off[i0 + min(lane, 32)];

  int idxA[4], idxB[4], dAs[4], dBs[4];
#pragma unroll
  for (int p = 0; p < 4; ++p) {
    int base = slot * 2 + p * 8;
    int eA  = __shfl(offv, base + 0);
    int eB  = __shfl(offv, base + 1);
    int eB1 = __shfl(offv, base + 2);
    dAs[p] = eB - eA;
    dBs[p] = eB1 - eB;
    int adrA = (dAs[p] > 0) ? min(eA + lane, eB - 1) : 0;
    int adrB = (dBs[p] > 0) ? min(eB + lane, eB1 - 1) : 0;
    idxA[p] = csr[adrA];
    idxB[p] = csr[adrB];
  }

  float sx = 0.f, sy = 0.f, ssx = 0.f, ssy = 0.f;

#pragma unroll
  for (int p = 0; p < 4; ++p) {
    int rA = i0 + slot * 2 + p * 8;
    int rB = rA + 1;
    int degA = dAs[p], degB = dBs[p];
    float dA = dinv[rA], dB = dinv[rB];

    unsigned int sU = *(const unsigned int*)(g + (size_t)rA * 128 + c0);
    unsigned int sV = *(const unsigned int*)(g + (size_t)rB * 128 + c0);
    float2 accA = make_float2(bf2f((ushort_t)(sU & 0xffffu)),
                              bf2f((ushort_t)(sU >> 16)));
    float2 accB = make_float2(bf2f((ushort_t)(sV & 0xffffu)),
                              bf2f((ushort_t)(sV >> 16)));

    int dAf = min(degA, 64), dBf = min(degB, 64);
    int nc = (max(dAf, dBf) + 7) >> 3;
    if (nc > 0) {
      unsigned int vA[8], vB[8];
      gather8(g, c0, idxA[p], 0, vA);
      gather8(g, c0, idxB[p], 0, vB);
      for (int q = 1; q < nc; ++q) {
        unsigned int wA[8], wB[8];
        gather8(g, c0, idxA[p], q, wA);
        gather8(g, c0, idxB[p], q, wB);
        consume8(accA, vA, q - 1, dAf);
        consume8(accB, vB, q - 1, dBf);
#pragma unroll
        for (int k = 0; k < 8; ++k) { vA[k] = wA[k]; vB[k] = wB[k]; }
      }
      consume8(accA, vA, nc - 1, dAf);
      consume8(accB, vB, nc - 1, dBf);
    }

    if (degA > 64) {
      int eA = __shfl(offv, slot * 2 + p * 8);
      for (int e = eA + 64; e < eA + degA; ++e) {
        int idx = csr[e];
        unsigned int v = *(const unsigned int*)(g + (size_t)idx * 128 + c0);
        accA.x += bf2f((ushort_t)(v & 0xffffu));
        accA.y += bf2f((ushort_t)(v >> 16));
      }
    }
    if (degB > 64) {
      int eB = __shfl(offv, slot * 2 + p * 8 + 1);
      for (int e = eB + 64; e < eB + degB; ++e) {
        int idx = csr[e];
        unsigned int v = *(const unsigned int*)(g + (size_t)idx * 128 + c0);
        accB.x += bf2f((ushort_t)(v & 0xffffu));
        accB.y += bf2f((ushort_t)(v >> 16));
      }
    }

    accA.x *= dA; accA.y *= dA;
    accB.x *= dB; accB.y *= dB;
    unsigned int oA = (unsigned int)f2bf(accA.x) | ((unsigned int)f2bf(accA.y) << 16);
    unsigned int oB = (unsigned int)f2bf(accB.x) | ((unsigned int)f2bf(accB.y) << 16);
    *(unsigned int*)(outb + (size_t)rA * 128 + c0) = oA;
    *(unsigned int*)(outb + (size_t)rB * 128 + c0) = oB;
    sx += accA.x + accB.x;
    sy += accA.y + accB.y;
    ssx = fmaf(accA.x, accA.x, ssx); ssx = fmaf(accB.x, accB.x, ssx);
    ssy = fmaf(accA.y, accA.y, ssy); ssy = fmaf(accB.y, accB.y, ssy);
  }

  atomicAdd(&ls[c0 + 0], sx);
  atomicAdd(&ls[c0 + 1], sy);
  atomicAdd(&lss[c0 + 0], ssx);
  atomicAdd(&lss[c0 + 1], ssy);
  __syncthreads();
  if (t < 128) {
    atomicAdd(&stats[t], ls[t]);
    atomicAdd(&stats[t + 128], lss[t]);
  }
}

// fused per-graph pooling (both entities)
__global__ __launch_bounds__(128)
void gk_pool2(const ushort_t* __restrict__ Al, const ushort_t* __restrict__ Ar,
              const float* __restrict__ statsAll,
              const float* __restrict__ gml, const float* __restrict__ btl,
              const float* __restrict__ gmr, const float* __restrict__ btr,
              float* __restrict__ z) {
  bool isl = blockIdx.x < NGRAPH;
  int gidx = isl ? blockIdx.x : blockIdx.x - NGRAPH;
  const ushort_t* A = isl ? Al : Ar;
  const float* stats = statsAll + (isl ? 0 : 256);
  const float* gamma = isl ? gml : gmr;
  const float* beta = isl ? btl : btr;
  float inv_n = isl ? (1.f / (float)NLIG) : (1.f / (float)NREC);
  int npg = isl ? (NLIG / NGRAPH) : (NREC / NGRAPH);
  int zoff = isl ? 0 : EMB;

  int c = threadIdx.x;
  float mu = stats[c] * inv_n;
  float var = stats[128 + c] * inv_n - mu * mu;
  float scl = gamma[c] * rsqrtf(var + BN_EPS);
  float be = beta[c];
  float sum = 0.f;
  int r0 = gidx * npg;
  for (int r = 0; r < npg; ++r) {
    float v = (bf2f(A[(size_t)(r0 + r) * 128 + c]) - mu) * scl + be;
    sum += v > 0.f ? v : 0.f;
  }
  z[(size_t)gidx * 256 + zoff + c] = sum * (1.0f / (float)npg);
}

__global__ __launch_bounds__(128)
void gk_mlp(const float* __restrict__ z, const float* __restrict__ w1,
            const float* __restrict__ b1, const float* __restrict__ w2,
            const float* __restrict__ b2, float* __restrict__ out) {
  __shared__ float zs[256];
  __shared__ float red[128];
  int gidx = blockIdx.x, t = threadIdx.x;
  zs[t] = z[(size_t)gidx * 256 + t];
  zs[t + 128] = z[(size_t)gidx * 256 + 128 + t];
  __syncthreads();
  float acc = b1[t];
  for (int k = 0; k < 256; ++k) acc += zs[k] * w1[(size_t)k * 128 + t];
  acc = (acc > 0.f ? acc : 0.f) * w2[t];
  red[t] = acc;
  __syncthreads();
  for (int o = 64; o > 0; o >>= 1) {
    if (t < o) red[t] += red[t + o];
    __syncthreads();
  }
  if (t == 0) out[gidx] = red[0] + b2[0];
}

// ============================ launch ============================

extern "C" void kernel_launch(void* const* d_in, const int* in_sizes, int n_in,
                              void* d_out, int out_size, void* d_ws, size_t ws_size,
                              hipStream_t stream) {
  (void)in_sizes; (void)n_in; (void)out_size; (void)ws_size;
  const int*   lig_x       = (const int*)  d_in[0];
  const int*   rec_x_int   = (const int*)  d_in[1];
  const float* rec_x_float = (const float*)d_in[2];
  const int*   lig_ei      = (const int*)  d_in[3];
  const int*   rec_ei      = (const int*)  d_in[4];
  const int*   atom_off    = (const int*)  d_in[7];
  const float* atom_emb    = (const float*)d_in[8];
  const float* rec_emb1    = (const float*)d_in[9];
  const float* rec_w       = (const float*)d_in[10];
  const float* rec_b       = (const float*)d_in[11];
  const float* lig_W       = (const float*)d_in[12];
  const float* lig_gamma   = (const float*)d_in[14];
  const float* lig_beta    = (const float*)d_in[15];
  const float* rec_W       = (const float*)d_in[16];
  const float* rec_gamma   = (const float*)d_in[18];
  const float* rec_beta    = (const float*)d_in[19];
  const float* out_w1      = (const float*)d_in[20];
  const float* out_b1      = (const float*)d_in[21];
  const float* out_w2      = (const float*)d_in[22];
  const float* out_b2      = (const float*)d_in[23];
  float* out = (float*)d_out;

  char* p = (char*)d_ws;
  auto alloc = [&](size_t bytes) -> void* {
    void* r = p;
    p += (bytes + 255) & ~(size_t)255;
    return r;
  };
  ushort_t* Ab_r   = (ushort_t*)alloc((size_t)NREC * EMB * 2);  // rec features bf16
  ushort_t* Gb_r   = (ushort_t*)alloc((size_t)NREC * EMB * 2);  // rec g bf16
  ushort_t* Ab_l   = (ushort_t*)alloc((size_t)NLIG * EMB * 2);  // lig features bf16
  ushort_t* Gb_l   = (ushort_t*)alloc((size_t)NLIG * EMB * 2);  // lig g bf16
  ushort_t* Wtb_l  = (ushort_t*)alloc((size_t)EMB * EMB * 2);
  ushort_t* Wtb_r  = (ushort_t*)alloc((size_t)EMB * EMB * 2);
  ushort_t* WtK    = (ushort_t*)alloc((size_t)EMB * 224 * 2);   // rec_w^T bf16, K-padded
  ushort_t* Xb2    = (ushort_t*)alloc(((size_t)NREC * 200 + 64) * 2);  // bf16 X, padded rows
  float* scl_l     = (float*)alloc(128 * 4);
  float* sh_l      = (float*)alloc(128 * 4);
  float* scl_r     = (float*)alloc(128 * 4);
  float* sh_r      = (float*)alloc(128 * 4);
  float* dinv_lig  = (float*)alloc((size_t)NLIG * 4);
  float* dinv_rec  = (float*)alloc((size_t)NREC * 4);
  int*   cnt_lig   = (int*)  alloc((size_t)NLIG * 4);
  int*   cnt_rec   = (int*)  alloc((size_t)NREC * 4);
  int*   off_lig   = (int*)  alloc((size_t)(NLIG + 8) * 4);
  int*   off_rec   = (int*)  alloc((size_t)(NREC + 8) * 4);
  int*   csr_lig   = (int*)  alloc((size_t)ELIG * 4);
  int*   csr_rec   = (int*)  alloc((size_t)EREC * 4);
  int*   bsum_lig  = (int*)  alloc(256 * 4);
  int*   bsum_rec  = (int*)  alloc(256 * 4);
  float* stats2    = (float*)alloc(512 * 4);   // [0..255] lig, [256..511] rec
  float* z         = (float*)alloc((size_t)NGRAPH * 256 * 4);

  // ---- CSR build ----
  hipMemsetAsync(cnt_lig, 0, (size_t)NLIG * 4, stream);
  hipMemsetAsync(cnt_rec, 0, (size_t)NREC * 4, stream);
  gk_count<<<ELIG / 256, 256, 0, stream>>>(lig_ei + ELIG, cnt_lig, ELIG);
  gk_count<<<EREC / 256, 256, 0, stream>>>(rec_ei + EREC, cnt_rec, EREC);
  gk_scan1<<<NLIG / 1024, 256, 0, stream>>>(cnt_lig, off_lig, bsum_lig, NLIG);
  gk_scan2<<<1, 256, 0, stream>>>(bsum_lig, NLIG / 1024);
  gk_scan3f<<<NLIG / 256, 256, 0, stream>>>(off_lig, bsum_lig, cnt_lig,
                                            dinv_lig, NLIG, ELIG);
  gk_scan1<<<NREC / 1024, 256, 0, stream>>>(cnt_rec, off_rec, bsum_rec, NREC);
  gk_scan2<<<1, 256, 0, stream>>>(bsum_rec, NREC / 1024);
  gk_scan3f<<<NREC / 256, 256, 0, stream>>>(off_rec, bsum_rec, cnt_rec,
                                            dinv_rec, NREC, EREC);
  gk_fill<<<ELIG / 256, 256, 0, stream>>>(lig_ei, lig_ei + ELIG, cnt_lig, csr_lig, ELIG);
  gk_fill<<<EREC / 256, 256, 0, stream>>>(rec_ei, rec_ei + EREC, cnt_rec, csr_rec, EREC);

  // ---- encoders ----
  gk_recw2<<<112, 256, 0, stream>>>(rec_w, WtK);
  gk_xcast<<<2048, 256, 0, stream>>>(rec_x_float, Xb2);
  gk_enc2<<<LIGB + NREC / 128, 256, 0, stream>>>(lig_x, atom_off, atom_emb,
                                                 Xb2, rec_x_int, rec_emb1,
                                                 WtK, rec_b, Ab_l, Ab_r);

  // ---- fused 3-layer towers ----
  for (int l = 0; l < 3; ++l) {
    const float* Wl = lig_W + (size_t)l * EMB * EMB;
    const float* Wr = rec_W + (size_t)l * EMB * EMB;
    const float* gml = (l > 0) ? lig_gamma + (size_t)(l - 1) * EMB : lig_gamma;
    const float* btl = (l > 0) ? lig_beta + (size_t)(l - 1) * EMB : lig_beta;
    const float* gmr = (l > 0) ? rec_gamma + (size_t)(l - 1) * EMB : rec_gamma;
    const float* btr = (l > 0) ? rec_beta + (size_t)(l - 1) * EMB : rec_beta;
    gk_prep2<<<128, 256, 0, stream>>>(Wl, Wr, stats2, gml, btl, gmr, btr,
                                      l > 0 ? 1 : 0, Wtb_l, Wtb_r,
                                      scl_l, sh_l, scl_r, sh_r);
    hipMemsetAsync(stats2, 0, 512 * 4, stream);
    gk_mm2<<<MMB_L + NREC / 128, 256, 0, stream>>>(
        Ab_l, Ab_r, Wtb_l, Wtb_r, scl_l, sh_l, scl_r, sh_r, l > 0 ? 1 : 0,
        dinv_lig, dinv_rec, Gb_l, Gb_r);
    gk_agg2<<<AGB_L + NREC / 32, 256, 0, stream>>>(
        Gb_l, Gb_r, off_lig, off_rec, csr_lig, csr_rec,
        dinv_lig, dinv_rec, Ab_l, Ab_r, stats2);
  }

  // ---- pool + head ----
  gk_pool2<<<2 * NGRAPH, 128, 0, stream>>>(Ab_l, Ab_r, stats2,
                                           lig_gamma + 2 * EMB, lig_beta + 2 * EMB,
                                           rec_gamma + 2 * EMB, rec_beta + 2 * EMB, z);
  gk_mlp<<<NGRAPH, 128, 0, stream>>>(z, out_w1, out_b1, out_w2, out_b2, out);
}

// Round 8
// 1732.698 us; speedup vs baseline: 1.4119x; 1.0357x over previous
//
#include <hip/hip_runtime.h>
#include <hip/hip_bf16.h>
#include <cstdint>
#include <cstddef>

#define EMB 128
#define NLIG 32768
#define NREC 262144
#define NGRAPH 1024
#define ELIG 327680
#define EREC 2097152
#define BN_EPS 1e-5f

typedef unsigned short ushort_t;
typedef short bf16x8 __attribute__((ext_vector_type(8)));
typedef float f32x4 __attribute__((ext_vector_type(4)));

__device__ __forceinline__ float bf2f(ushort_t u) {
  union { unsigned int i; float f; } v;
  v.i = ((unsigned int)u) << 16;
  return v.f;
}
__device__ __forceinline__ ushort_t f2bf(float f) {
  __hip_bfloat16 h = __float2bfloat16(f);  // RNE
  union { __hip_bfloat16 h; ushort_t u; } v;
  v.h = h;
  return v.u;
}

// ============================ CSR build (fused) ============================

// Phase A: count_lig + count_rec + recw2 + xcast, one dispatch.
#define PA_CL (ELIG / 256)          // 1280
#define PA_CR (EREC / 256)          // 8192
#define PA_CW 112
#define PA_CX 2048
__global__ __launch_bounds__(256)
void gk_phaseA(const int* __restrict__ lig_dst, const int* __restrict__ rec_dst,
               int* __restrict__ cnt_l, int* __restrict__ cnt_r,
               const float* __restrict__ W, ushort_t* __restrict__ Wt,
               const float* __restrict__ X, ushort_t* __restrict__ Xb) {
  int b = blockIdx.x;
  int t = threadIdx.x;
  if (b < PA_CL) {
    int e = b * 256 + t;
    atomicAdd(&cnt_l[lig_dst[e]], 1);
    return;
  }
  b -= PA_CL;
  if (b < PA_CR) {
    int e = b * 256 + t;
    atomicAdd(&cnt_r[rec_dst[e]], 1);
    return;
  }
  b -= PA_CR;
  if (b < PA_CW) {
    int idx = b * 256 + t;  // 128*224 = 28672 total
    if (idx < 128 * 224) {
      int c = idx / 224, k = idx - c * 224;
      Wt[idx] = (k < 199) ? f2bf(W[(size_t)k * 128 + c]) : (ushort_t)0;
    }
    return;
  }
  b -= PA_CW;
  // xcast: fp32 -> bf16, row-padded [NREC][200]
  const int ITEMS = NREC * 25;
  int stride = PA_CX * 256;
  for (int v = b * 256 + t; v < ITEMS; v += stride) {
    int row = v / 25, sub = v - row * 25;
    int k0 = sub * 8;
    const float* xr = X + (size_t)row * 199 + k0;
    ushort_t tmp[8];
#pragma unroll
    for (int j = 0; j < 8; ++j) {
      float f = (k0 + j < 199) ? xr[j] : 0.f;
      tmp[j] = f2bf(f);
    }
    *(uint4*)(Xb + (size_t)row * 200 + k0) = *(uint4*)tmp;
  }
}

__device__ __forceinline__ void scan1_body(const int* __restrict__ cnt,
                                           int* __restrict__ off,
                                           int* __restrict__ bsum,
                                           int n, int blk, int* sm) {
  int t = threadIdx.x;
  int base = blk * 1024 + t * 4;
  int v0 = (base + 0 < n) ? cnt[base + 0] : 0;
  int v1 = (base + 1 < n) ? cnt[base + 1] : 0;
  int v2 = (base + 2 < n) ? cnt[base + 2] : 0;
  int v3 = (base + 3 < n) ? cnt[base + 3] : 0;
  int loc = v0 + v1 + v2 + v3;
  sm[t] = loc;
  __syncthreads();
  for (int o = 1; o < 256; o <<= 1) {
    int x = (t >= o) ? sm[t - o] : 0;
    __syncthreads();
    sm[t] += x;
    __syncthreads();
  }
  int run = sm[t] - loc;
  if (base + 0 < n) off[base + 0] = run;
  run += v0;
  if (base + 1 < n) off[base + 1] = run;
  run += v1;
  if (base + 2 < n) off[base + 2] = run;
  run += v2;
  if (base + 3 < n) off[base + 3] = run;
  if (t == 255) bsum[blk] = sm[255];
}

#define S1_L (NLIG / 1024)   // 32
#define S1_R (NREC / 1024)   // 256
__global__ __launch_bounds__(256)
void gk_scan1b(const int* __restrict__ cnt_l, int* __restrict__ off_l,
               int* __restrict__ bsum_l,
               const int* __restrict__ cnt_r, int* __restrict__ off_r,
               int* __restrict__ bsum_r) {
  __shared__ int sm[256];
  int b = blockIdx.x;
  if (b < S1_L) scan1_body(cnt_l, off_l, bsum_l, NLIG, b, sm);
  else          scan1_body(cnt_r, off_r, bsum_r, NREC, b - S1_L, sm);
}

__device__ __forceinline__ void scan2_body(int* __restrict__ bsum, int nb,
                                           int* sm) {
  int t = threadIdx.x;
  int v = (t < nb) ? bsum[t] : 0;
  sm[t] = v;
  __syncthreads();
  for (int o = 1; o < 256; o <<= 1) {
    int x = (t >= o) ? sm[t - o] : 0;
    __syncthreads();
    sm[t] += x;
    __syncthreads();
  }
  if (t < nb) bsum[t] = sm[t] - v;
}

__global__ __launch_bounds__(256)
void gk_scan2b(int* __restrict__ bsum_l, int* __restrict__ bsum_r) {
  __shared__ int sm[256];
  if (blockIdx.x == 0) scan2_body(bsum_l, S1_L, sm);
  else                 scan2_body(bsum_r, S1_R, sm);
}

__device__ __forceinline__ void scan3_body(int* __restrict__ off,
                                           const int* __restrict__ bsum,
                                           int* __restrict__ cur,
                                           float* __restrict__ dinv,
                                           int n, int E, int blk) {
  int i = blk * 256 + threadIdx.x;
  if (i < n) {
    int deg = cur[i];
    int o = off[i] + bsum[i >> 10];
    off[i] = o;
    cur[i] = o;
    dinv[i] = rsqrtf((float)(deg + 1));
  }
  if (i == 0) off[n] = E;
}

#define S3_L (NLIG / 256)   // 128
#define S3_R (NREC / 256)   // 1024
__global__ __launch_bounds__(256)
void gk_scan3b(int* __restrict__ off_l, const int* __restrict__ bsum_l,
               int* __restrict__ cur_l, float* __restrict__ dinv_l,
               int* __restrict__ off_r, const int* __restrict__ bsum_r,
               int* __restrict__ cur_r, float* __restrict__ dinv_r) {
  int b = blockIdx.x;
  if (b < S3_L) scan3_body(off_l, bsum_l, cur_l, dinv_l, NLIG, ELIG, b);
  else          scan3_body(off_r, bsum_r, cur_r, dinv_r, NREC, EREC, b - S3_L);
}

// ============== Phase E: fill_lig + fill_rec + fused encoders ==============
// blocks: [0,1280) fill lig | [1280,9472) fill rec |
//         [9472, 9472+16384) lig encoder | [+2048) rec MFMA encoder.
#define PE_FL (ELIG / 256)    // 1280
#define PE_FR (EREC / 256)    // 8192
#define LIGB (NLIG / 2)       // 16384
__global__ __launch_bounds__(256)
void gk_phaseE(const int* __restrict__ lig_ei, const int* __restrict__ rec_ei,
               int* __restrict__ cur_l, int* __restrict__ cur_r,
               int* __restrict__ csr_l, int* __restrict__ csr_r,
               const int* __restrict__ lig_x, const int* __restrict__ offs,
               const float* __restrict__ emb,
               const ushort_t* __restrict__ Xb, const int* __restrict__ xi,
               const float* __restrict__ emb1, const ushort_t* __restrict__ Wt,
               const float* __restrict__ b,
               ushort_t* __restrict__ Al, ushort_t* __restrict__ Ar) {
  int blk = blockIdx.x;
  int t = threadIdx.x;
  if (blk < PE_FL) {
    int e = blk * 256 + t;
    int d = lig_ei[ELIG + e];
    int pos = atomicAdd(&cur_l[d], 1);
    csr_l[pos] = lig_ei[e];
    return;
  }
  blk -= PE_FL;
  if (blk < PE_FR) {
    int e = blk * 256 + t;
    int d = rec_ei[EREC + e];
    int pos = atomicAdd(&cur_r[d], 1);
    csr_r[pos] = rec_ei[e];
    return;
  }
  blk -= PE_FR;
  if (blk < LIGB) {
    __shared__ int idx[2][9];
    int n0 = blk * 2;
    if (t < 9) idx[0][t] = lig_x[n0 * 9 + t] + offs[t];
    else if (t >= 128 && t < 137) idx[1][t - 128] = lig_x[(n0 + 1) * 9 + (t - 128)] + offs[t - 128];
    __syncthreads();
    int half = t >> 7, c = t & 127;
    float acc = 0.f;
#pragma unroll
    for (int f = 0; f < 9; ++f) acc += emb[(size_t)idx[half][f] * EMB + c];
    Al[(size_t)(n0 + half) * EMB + c] = f2bf(acc);
    return;
  }
  // ---- rec encoder (LDS-free / barrier-free), verified ----
  int row0 = (blk - LIGB) * 128;
  int w = t >> 6, lane = t & 63;
  int m = lane & 15, quad = lane >> 4;
  int rbase = w * 32;
  int rA = row0 + rbase + m;
  int rB = rA + 16;

  f32x4 acc[2][8];
#pragma unroll
  for (int rt = 0; rt < 2; ++rt)
#pragma unroll
    for (int ct = 0; ct < 8; ++ct) acc[rt][ct] = (f32x4){0.f, 0.f, 0.f, 0.f};

  const ushort_t* xpA = Xb + (size_t)rA * 200 + quad * 8;
  const ushort_t* xpB = Xb + (size_t)rB * 200 + quad * 8;
  const ushort_t* wp = Wt + (size_t)m * 224 + quad * 8;

  for (int ch = 0; ch < 7; ++ch) {
    bf16x8 a0 = *(const bf16x8*)(xpA + ch * 32);
    bf16x8 a1 = *(const bf16x8*)(xpB + ch * 32);
#pragma unroll
    for (int ct = 0; ct < 8; ++ct) {
      bf16x8 bb = *(const bf16x8*)(wp + (size_t)ct * 16 * 224 + ch * 32);
      acc[0][ct] = __builtin_amdgcn_mfma_f32_16x16x32_bf16(a0, bb, acc[0][ct], 0, 0, 0);
      acc[1][ct] = __builtin_amdgcn_mfma_f32_16x16x32_bf16(a1, bb, acc[1][ct], 0, 0, 0);
    }
  }

  float bcol[8];
#pragma unroll
  for (int ct = 0; ct < 8; ++ct) bcol[ct] = b[ct * 16 + m];
#pragma unroll
  for (int rt = 0; rt < 2; ++rt) {
    int rb = row0 + rbase + rt * 16 + quad * 4;
#pragma unroll
    for (int rr = 0; rr < 4; ++rr) {
      int row = rb + rr;
      const float* e = emb1 + (size_t)xi[row] * 128;
#pragma unroll
      for (int ct = 0; ct < 8; ++ct) {
        int c = ct * 16 + m;
        float v = acc[rt][ct][rr] + bcol[ct] + e[c];
        Ar[(size_t)row * 128 + c] = f2bf(v);
      }
    }
  }
}

// ======================= fused per-layer prep (both entities) =======================
__global__ __launch_bounds__(256)
void gk_prep2(const float* __restrict__ Wl, const float* __restrict__ Wr,
              const float* __restrict__ statsAll,
              const float* __restrict__ gml, const float* __restrict__ btl,
              const float* __restrict__ gmr, const float* __restrict__ btr,
              int donorm,
              ushort_t* __restrict__ Wtl, ushort_t* __restrict__ Wtr,
              float* __restrict__ scll, float* __restrict__ shl,
              float* __restrict__ sclr, float* __restrict__ shr) {
  int bidx = blockIdx.x;
  bool isl = bidx < 64;
  const float* W = isl ? Wl : Wr;
  const float* stats = statsAll + (isl ? 0 : 256);
  const float* gamma = isl ? gml : gmr;
  const float* beta = isl ? btl : btr;
  float inv_n = isl ? (1.f / (float)NLIG) : (1.f / (float)NREC);
  ushort_t* Wt = isl ? Wtl : Wtr;
  float* bnscl = isl ? scll : sclr;
  float* bnsh = isl ? shl : shr;
  int idx = (isl ? bidx : bidx - 64) * 256 + threadIdx.x;
  if (idx < 128) {
    if (donorm) {
      float mu = stats[idx] * inv_n;
      float var = stats[128 + idx] * inv_n - mu * mu;
      float s = gamma[idx] * rsqrtf(var + BN_EPS);
      bnscl[idx] = s;
      bnsh[idx] = beta[idx] - mu * s;
    } else {
      bnscl[idx] = 1.f;
      bnsh[idx] = 0.f;
    }
  }
  int c = idx >> 7, k = idx & 127;
  Wt[(size_t)c * 128 + k] = f2bf(W[(size_t)k * 128 + c]);
}

// ====================== fused MFMA GCN GEMM (both entities) ======================
#define MMB_L (NLIG / 128)
__global__ __launch_bounds__(256)
void gk_mm2(const ushort_t* __restrict__ Xl, const ushort_t* __restrict__ Xr,
            const ushort_t* __restrict__ Wtl, const ushort_t* __restrict__ Wtr,
            const float* __restrict__ scll, const float* __restrict__ shl,
            const float* __restrict__ sclr, const float* __restrict__ shr,
            int donorm,
            const float* __restrict__ dinvl, const float* __restrict__ dinvr,
            ushort_t* __restrict__ gbl, ushort_t* __restrict__ gbr) {
  bool isl = blockIdx.x < MMB_L;
  const ushort_t* Xb = isl ? Xl : Xr;
  const ushort_t* Wt = isl ? Wtl : Wtr;
  const float* bnscl = isl ? scll : sclr;
  const float* bnsh = isl ? shl : shr;
  const float* dinv = isl ? dinvl : dinvr;
  ushort_t* gb = isl ? gbl : gbr;
  int row0 = (isl ? blockIdx.x : blockIdx.x - MMB_L) * 128;

  __shared__ ushort_t Xs[128 * 128];
  __shared__ ushort_t Ws[128 * 128];
  int t = threadIdx.x;

  for (int i = t; i < 2048; i += 256) {
    int r = i >> 4, cc = i & 15;
    union { uint4 v; ushort_t s[8]; } u;
    u.v = *(const uint4*)(Xb + (size_t)(row0 + r) * 128 + cc * 8);
    if (donorm) {
#pragma unroll
      for (int j = 0; j < 8; ++j) {
        int k = cc * 8 + j;
        float f = fmaf(bf2f(u.s[j]), bnscl[k], bnsh[k]);
        f = f > 0.f ? f : 0.f;
        u.s[j] = f2bf(f);
      }
    }
    *(uint4*)&Xs[r * 128 + ((cc ^ (r & 15)) * 8)] = u.v;
  }
  for (int i = t; i < 2048; i += 256) {
    int c = i >> 4, cc = i & 15;
    uint4 u = *(const uint4*)(Wt + (size_t)c * 128 + cc * 8);
    *(uint4*)&Ws[c * 128 + ((cc ^ (c & 15)) * 8)] = u;
  }
  __syncthreads();

  int w = t >> 6, lane = t & 63;
  int m = lane & 15, quad = lane >> 4;
  int rbase = w * 32;

  f32x4 acc[2][8];
#pragma unroll
  for (int rt = 0; rt < 2; ++rt)
#pragma unroll
    for (int ct = 0; ct < 8; ++ct) acc[rt][ct] = (f32x4){0.f, 0.f, 0.f, 0.f};

#pragma unroll
  for (int kc8 = 0; kc8 < 16; kc8 += 4) {
    int ck = (kc8 + quad) ^ m;
    bf16x8 a0 = *(const bf16x8*)&Xs[(rbase + m) * 128 + ck * 8];
    bf16x8 a1 = *(const bf16x8*)&Xs[(rbase + 16 + m) * 128 + ck * 8];
#pragma unroll
    for (int ct = 0; ct < 8; ++ct) {
      bf16x8 b = *(const bf16x8*)&Ws[(ct * 16 + m) * 128 + ck * 8];
      acc[0][ct] = __builtin_amdgcn_mfma_f32_16x16x32_bf16(a0, b, acc[0][ct], 0, 0, 0);
      acc[1][ct] = __builtin_amdgcn_mfma_f32_16x16x32_bf16(a1, b, acc[1][ct], 0, 0, 0);
    }
  }

#pragma unroll
  for (int rt = 0; rt < 2; ++rt) {
    int rb = row0 + rbase + rt * 16 + quad * 4;
    float d0 = dinv[rb + 0], d1 = dinv[rb + 1];
    float d2 = dinv[rb + 2], d3 = dinv[rb + 3];
#pragma unroll
    for (int ct = 0; ct < 8; ++ct) {
      int c = ct * 16 + m;
      gb[(size_t)(rb + 0) * 128 + c] = f2bf(acc[rt][ct][0] * d0);
      gb[(size_t)(rb + 1) * 128 + c] = f2bf(acc[rt][ct][1] * d1);
      gb[(size_t)(rb + 2) * 128 + c] = f2bf(acc[rt][ct][2] * d2);
      gb[(size_t)(rb + 3) * 128 + c] = f2bf(acc[rt][ct][3] * d3);
    }
  }
}

// ---------------- fused aggregation (verified v3 body, both entities) ----------------

__device__ __forceinline__ void gather8(const ushort_t* __restrict__ g, int c0,
                                        int idxv, int q, unsigned int* v) {
#pragma unroll
  for (int k = 0; k < 8; ++k) {
    int idx = __shfl(idxv, q * 8 + k);
    v[k] = *(const unsigned int*)(g + (size_t)idx * 128 + c0);
  }
}

__device__ __forceinline__ void consume8(float2& acc, const unsigned int* v,
                                         int q, int deg) {
#pragma unroll
  for (int k = 0; k < 8; ++k) {
    float m = (q * 8 + k < deg) ? 1.f : 0.f;
    acc.x = fmaf(bf2f((ushort_t)(v[k] & 0xffffu)), m, acc.x);
    acc.y = fmaf(bf2f((ushort_t)(v[k] >> 16)), m, acc.y);
  }
}

#define AGB_L (NLIG / 32)
__global__ __launch_bounds__(256)
void gk_agg2(const ushort_t* __restrict__ gl, const ushort_t* __restrict__ gr,
             const int* __restrict__ offl, const int* __restrict__ offr,
             const int* __restrict__ csrl, const int* __restrict__ csrr,
             const float* __restrict__ dinvl, const float* __restrict__ dinvr,
             ushort_t* __restrict__ outl, ushort_t* __restrict__ outr,
             float* __restrict__ statsAll) {
  bool isl = blockIdx.x < AGB_L;
  const ushort_t* g = isl ? gl : gr;
  const int* off = isl ? offl : offr;
  const int* csr = isl ? csrl : csrr;
  const float* dinv = isl ? dinvl : dinvr;
  ushort_t* outb = isl ? outl : outr;
  float* stats = statsAll + (isl ? 0 : 256);
  int i0 = (isl ? blockIdx.x : blockIdx.x - AGB_L) * 32;

  __shared__ float ls[128];
  __shared__ float lss[128];
  int t = threadIdx.x;
  int slot = t >> 6;
  int lane = t & 63;
  int c0 = lane * 2;

  if (t < 128) { ls[t] = 0.f; lss[t] = 0.f; }
  __syncthreads();

  int offv = off[i0 + min(lane, 32)];

  int idxA[4], idxB[4], dAs[4], dBs[4];
#pragma unroll
  for (int p = 0; p < 4; ++p) {
    int base = slot * 2 + p * 8;
    int eA  = __shfl(offv, base + 0);
    int eB  = __shfl(offv, base + 1);
    int eB1 = __shfl(offv, base + 2);
    dAs[p] = eB - eA;
    dBs[p] = eB1 - eB;
    int adrA = (dAs[p] > 0) ? min(eA + lane, eB - 1) : 0;
    int adrB = (dBs[p] > 0) ? min(eB + lane, eB1 - 1) : 0;
    idxA[p] = csr[adrA];
    idxB[p] = csr[adrB];
  }

  float sx = 0.f, sy = 0.f, ssx = 0.f, ssy = 0.f;

#pragma unroll
  for (int p = 0; p < 4; ++p) {
    int rA = i0 + slot * 2 + p * 8;
    int rB = rA + 1;
    int degA = dAs[p], degB = dBs[p];
    float dA = dinv[rA], dB = dinv[rB];

    unsigned int sU = *(const unsigned int*)(g + (size_t)rA * 128 + c0);
    unsigned int sV = *(const unsigned int*)(g + (size_t)rB * 128 + c0);
    float2 accA = make_float2(bf2f((ushort_t)(sU & 0xffffu)),
                              bf2f((ushort_t)(sU >> 16)));
    float2 accB = make_float2(bf2f((ushort_t)(sV & 0xffffu)),
                              bf2f((ushort_t)(sV >> 16)));

    int dAf = min(degA, 64), dBf = min(degB, 64);
    int nc = (max(dAf, dBf) + 7) >> 3;
    if (nc > 0) {
      unsigned int vA[8], vB[8];
      gather8(g, c0, idxA[p], 0, vA);
      gather8(g, c0, idxB[p], 0, vB);
      for (int q = 1; q < nc; ++q) {
        unsigned int wA[8], wB[8];
        gather8(g, c0, idxA[p], q, wA);
        gather8(g, c0, idxB[p], q, wB);
        consume8(accA, vA, q - 1, dAf);
        consume8(accB, vB, q - 1, dBf);
#pragma unroll
        for (int k = 0; k < 8; ++k) { vA[k] = wA[k]; vB[k] = wB[k]; }
      }
      consume8(accA, vA, nc - 1, dAf);
      consume8(accB, vB, nc - 1, dBf);
    }

    if (degA > 64) {
      int eA = __shfl(offv, slot * 2 + p * 8);
      for (int e = eA + 64; e < eA + degA; ++e) {
        int idx = csr[e];
        unsigned int v = *(const unsigned int*)(g + (size_t)idx * 128 + c0);
        accA.x += bf2f((ushort_t)(v & 0xffffu));
        accA.y += bf2f((ushort_t)(v >> 16));
      }
    }
    if (degB > 64) {
      int eB = __shfl(offv, slot * 2 + p * 8 + 1);
      for (int e = eB + 64; e < eB + degB; ++e) {
        int idx = csr[e];
        unsigned int v = *(const unsigned int*)(g + (size_t)idx * 128 + c0);
        accB.x += bf2f((ushort_t)(v & 0xffffu));
        accB.y += bf2f((ushort_t)(v >> 16));
      }
    }

    accA.x *= dA; accA.y *= dA;
    accB.x *= dB; accB.y *= dB;
    unsigned int oA = (unsigned int)f2bf(accA.x) | ((unsigned int)f2bf(accA.y) << 16);
    unsigned int oB = (unsigned int)f2bf(accB.x) | ((unsigned int)f2bf(accB.y) << 16);
    *(unsigned int*)(outb + (size_t)rA * 128 + c0) = oA;
    *(unsigned int*)(outb + (size_t)rB * 128 + c0) = oB;
    sx += accA.x + accB.x;
    sy += accA.y + accB.y;
    ssx = fmaf(accA.x, accA.x, ssx); ssx = fmaf(accB.x, accB.x, ssx);
    ssy = fmaf(accA.y, accA.y, ssy); ssy = fmaf(accB.y, accB.y, ssy);
  }

  atomicAdd(&ls[c0 + 0], sx);
  atomicAdd(&ls[c0 + 1], sy);
  atomicAdd(&lss[c0 + 0], ssx);
  atomicAdd(&lss[c0 + 1], ssy);
  __syncthreads();
  if (t < 128) {
    atomicAdd(&stats[t], ls[t]);
    atomicAdd(&stats[t + 128], lss[t]);
  }
}

// fused per-graph pooling (both entities)
__global__ __launch_bounds__(128)
void gk_pool2(const ushort_t* __restrict__ Al, const ushort_t* __restrict__ Ar,
              const float* __restrict__ statsAll,
              const float* __restrict__ gml, const float* __restrict__ btl,
              const float* __restrict__ gmr, const float* __restrict__ btr,
              float* __restrict__ z) {
  bool isl = blockIdx.x < NGRAPH;
  int gidx = isl ? blockIdx.x : blockIdx.x - NGRAPH;
  const ushort_t* A = isl ? Al : Ar;
  const float* stats = statsAll + (isl ? 0 : 256);
  const float* gamma = isl ? gml : gmr;
  const float* beta = isl ? btl : btr;
  float inv_n = isl ? (1.f / (float)NLIG) : (1.f / (float)NREC);
  int npg = isl ? (NLIG / NGRAPH) : (NREC / NGRAPH);
  int zoff = isl ? 0 : EMB;

  int c = threadIdx.x;
  float mu = stats[c] * inv_n;
  float var = stats[128 + c] * inv_n - mu * mu;
  float scl = gamma[c] * rsqrtf(var + BN_EPS);
  float be = beta[c];
  float sum = 0.f;
  int r0 = gidx * npg;
  for (int r = 0; r < npg; ++r) {
    float v = (bf2f(A[(size_t)(r0 + r) * 128 + c]) - mu) * scl + be;
    sum += v > 0.f ? v : 0.f;
  }
  z[(size_t)gidx * 256 + zoff + c] = sum * (1.0f / (float)npg);
}

__global__ __launch_bounds__(128)
void gk_mlp(const float* __restrict__ z, const float* __restrict__ w1,
            const float* __restrict__ b1, const float* __restrict__ w2,
            const float* __restrict__ b2, float* __restrict__ out) {
  __shared__ float zs[256];
  __shared__ float red[128];
  int gidx = blockIdx.x, t = threadIdx.x;
  zs[t] = z[(size_t)gidx * 256 + t];
  zs[t + 128] = z[(size_t)gidx * 256 + 128 + t];
  __syncthreads();
  float acc = b1[t];
  for (int k = 0; k < 256; ++k) acc += zs[k] * w1[(size_t)k * 128 + t];
  acc = (acc > 0.f ? acc : 0.f) * w2[t];
  red[t] = acc;
  __syncthreads();
  for (int o = 64; o > 0; o >>= 1) {
    if (t < o) red[t] += red[t + o];
    __syncthreads();
  }
  if (t == 0) out[gidx] = red[0] + b2[0];
}

// ============================ launch ============================

extern "C" void kernel_launch(void* const* d_in, const int* in_sizes, int n_in,
                              void* d_out, int out_size, void* d_ws, size_t ws_size,
                              hipStream_t stream) {
  (void)in_sizes; (void)n_in; (void)out_size; (void)ws_size;
  const int*   lig_x       = (const int*)  d_in[0];
  const int*   rec_x_int   = (const int*)  d_in[1];
  const float* rec_x_float = (const float*)d_in[2];
  const int*   lig_ei      = (const int*)  d_in[3];
  const int*   rec_ei      = (const int*)  d_in[4];
  const int*   atom_off    = (const int*)  d_in[7];
  const float* atom_emb    = (const float*)d_in[8];
  const float* rec_emb1    = (const float*)d_in[9];
  const float* rec_w       = (const float*)d_in[10];
  const float* rec_b       = (const float*)d_in[11];
  const float* lig_W       = (const float*)d_in[12];
  const float* lig_gamma   = (const float*)d_in[14];
  const float* lig_beta    = (const float*)d_in[15];
  const float* rec_W       = (const float*)d_in[16];
  const float* rec_gamma   = (const float*)d_in[18];
  const float* rec_beta    = (const float*)d_in[19];
  const float* out_w1      = (const float*)d_in[20];
  const float* out_b1      = (const float*)d_in[21];
  const float* out_w2      = (const float*)d_in[22];
  const float* out_b2      = (const float*)d_in[23];
  float* out = (float*)d_out;

  char* p = (char*)d_ws;
  auto alloc = [&](size_t bytes) -> void* {
    void* r = p;
    p += (bytes + 255) & ~(size_t)255;
    return r;
  };
  ushort_t* Ab_r   = (ushort_t*)alloc((size_t)NREC * EMB * 2);
  ushort_t* Gb_r   = (ushort_t*)alloc((size_t)NREC * EMB * 2);
  ushort_t* Ab_l   = (ushort_t*)alloc((size_t)NLIG * EMB * 2);
  ushort_t* Gb_l   = (ushort_t*)alloc((size_t)NLIG * EMB * 2);
  ushort_t* Wtb_l  = (ushort_t*)alloc((size_t)EMB * EMB * 2);
  ushort_t* Wtb_r  = (ushort_t*)alloc((size_t)EMB * EMB * 2);
  ushort_t* WtK    = (ushort_t*)alloc((size_t)EMB * 224 * 2);
  ushort_t* Xb2    = (ushort_t*)alloc(((size_t)NREC * 200 + 64) * 2);
  float* scl_l     = (float*)alloc(128 * 4);
  float* sh_l      = (float*)alloc(128 * 4);
  float* scl_r     = (float*)alloc(128 * 4);
  float* sh_r      = (float*)alloc(128 * 4);
  float* dinv_lig  = (float*)alloc((size_t)NLIG * 4);
  float* dinv_rec  = (float*)alloc((size_t)NREC * 4);
  int*   cnt_lig   = (int*)  alloc((size_t)NLIG * 4);
  int*   cnt_rec   = (int*)  alloc((size_t)NREC * 4);
  int*   off_lig   = (int*)  alloc((size_t)(NLIG + 8) * 4);
  int*   off_rec   = (int*)  alloc((size_t)(NREC + 8) * 4);
  int*   csr_lig   = (int*)  alloc((size_t)ELIG * 4);
  int*   csr_rec   = (int*)  alloc((size_t)EREC * 4);
  int*   bsum_lig  = (int*)  alloc(256 * 4);
  int*   bsum_rec  = (int*)  alloc(256 * 4);
  float* stats2    = (float*)alloc(512 * 4);   // [0..255] lig, [256..511] rec
  float* z         = (float*)alloc((size_t)NGRAPH * 256 * 4);

  // ---- CSR build + encoder prep (fused & overlapped) ----
  hipMemsetAsync(cnt_lig, 0, (size_t)NLIG * 4, stream);
  hipMemsetAsync(cnt_rec, 0, (size_t)NREC * 4, stream);
  gk_phaseA<<<PA_CL + PA_CR + PA_CW + PA_CX, 256, 0, stream>>>(
      lig_ei + ELIG, rec_ei + EREC, cnt_lig, cnt_rec, rec_w, WtK,
      rec_x_float, Xb2);
  gk_scan1b<<<S1_L + S1_R, 256, 0, stream>>>(cnt_lig, off_lig, bsum_lig,
                                             cnt_rec, off_rec, bsum_rec);
  gk_scan2b<<<2, 256, 0, stream>>>(bsum_lig, bsum_rec);
  gk_scan3b<<<S3_L + S3_R, 256, 0, stream>>>(off_lig, bsum_lig, cnt_lig, dinv_lig,
                                             off_rec, bsum_rec, cnt_rec, dinv_rec);
  gk_phaseE<<<PE_FL + PE_FR + LIGB + NREC / 128, 256, 0, stream>>>(
      lig_ei, rec_ei, cnt_lig, cnt_rec, csr_lig, csr_rec,
      lig_x, atom_off, atom_emb, Xb2, rec_x_int, rec_emb1, WtK, rec_b,
      Ab_l, Ab_r);

  // ---- fused 3-layer towers ----
  for (int l = 0; l < 3; ++l) {
    const float* Wl = lig_W + (size_t)l * EMB * EMB;
    const float* Wr = rec_W + (size_t)l * EMB * EMB;
    const float* gml = (l > 0) ? lig_gamma + (size_t)(l - 1) * EMB : lig_gamma;
    const float* btl = (l > 0) ? lig_beta + (size_t)(l - 1) * EMB : lig_beta;
    const float* gmr = (l > 0) ? rec_gamma + (size_t)(l - 1) * EMB : rec_gamma;
    const float* btr = (l > 0) ? rec_beta + (size_t)(l - 1) * EMB : rec_beta;
    gk_prep2<<<128, 256, 0, stream>>>(Wl, Wr, stats2, gml, btl, gmr, btr,
                                      l > 0 ? 1 : 0, Wtb_l, Wtb_r,
                                      scl_l, sh_l, scl_r, sh_r);
    hipMemsetAsync(stats2, 0, 512 * 4, stream);
    gk_mm2<<<MMB_L + NREC / 128, 256, 0, stream>>>(
        Ab_l, Ab_r, Wtb_l, Wtb_r, scl_l, sh_l, scl_r, sh_r, l > 0 ? 1 : 0,
        dinv_lig, dinv_rec, Gb_l, Gb_r);
    gk_agg2<<<AGB_L + NREC / 32, 256, 0, stream>>>(
        Gb_l, Gb_r, off_lig, off_rec, csr_lig, csr_rec,
        dinv_lig, dinv_rec, Ab_l, Ab_r, stats2);
  }

  // ---- pool + head ----
  gk_pool2<<<2 * NGRAPH, 128, 0, stream>>>(Ab_l, Ab_r, stats2,
                                           lig_gamma + 2 * EMB, lig_beta + 2 * EMB,
                                           rec_gamma + 2 * EMB, rec_beta + 2 * EMB, z);
  gk_mlp<<<NGRAPH, 128, 0, stream>>>(z, out_w1, out_b1, out_w2, out_b2, out);
}